// Round 12
// baseline (142.217 us; speedup 1.0000x reference)
//
#include <hip/hip_runtime.h>
#include <math.h>

#define BS        4
#define NQ        300
#define NK        17
#define LEN_Q     5100          // NQ*NK
#define N_HEADS   8
#define N_LEVELS  4
#define N_POINTS  4
#define D_MODEL   256
#define HD        32            // D_MODEL / N_HEADS

// transposed-value level bases (ushort/bf16 units), layout vt[l][n][s][c]
#define LB0 0
#define LB1 16777216            // + 32*16384*32
#define LB2 20971520            // + 32*4096*32
#define LB3 22020096            // + 32*1024*32
#define VT_TOTAL 22282240       // ushorts (44.6 MB)

#define NGEMM 957               // 3 x 319 GEMM blocks
#define NTRANS 21760            // 680 x 32 transpose tiles

typedef __attribute__((ext_vector_type(8))) short bf16x8;
typedef __attribute__((ext_vector_type(8))) unsigned short ushort8_t;
typedef __attribute__((ext_vector_type(4))) float f32x4;

// ---------------------------------------------------------------------------
// bf16 helpers (RNE)
// ---------------------------------------------------------------------------
__device__ __forceinline__ unsigned short f2bf(float x) {
    unsigned u = __float_as_uint(x);
    unsigned r = (u + 0x7fffu + ((u >> 16) & 1u)) >> 16;
    return (unsigned short)r;
}
__device__ __forceinline__ float bf2f(unsigned short s) {
    return __uint_as_float((unsigned)s << 16);
}
__device__ __forceinline__ bf16x8 cvt8(const float* __restrict__ p) {
    float4 a = *(const float4*)p;
    float4 b = *(const float4*)(p + 4);
    bf16x8 r;
    r[0] = f2bf(a.x); r[1] = f2bf(a.y); r[2] = f2bf(a.z); r[3] = f2bf(a.w);
    r[4] = f2bf(b.x); r[5] = f2bf(b.y); r[6] = f2bf(b.z); r[7] = f2bf(b.w);
    return r;
}

// ---------------------------------------------------------------------------
// fused prep: blocks [0,957) = proj MFMA GEMM; [957, 957+21760) = value
// transpose fp32->bf16. Independent work overlapped in one launch.
// ---------------------------------------------------------------------------
__global__ __launch_bounds__(256) void prep_kernel(
    const float* __restrict__ Q,
    const float* __restrict__ Woff, const float* __restrict__ boff,
    const float* __restrict__ Wattn, const float* __restrict__ battn,
    const float* __restrict__ v0, const float* __restrict__ v1,
    const float* __restrict__ v2, const float* __restrict__ v3,
    unsigned short* __restrict__ vt, float* __restrict__ P, int M)
{
    __shared__ float t[32][33];
    int bid = blockIdx.x;
    int tid = threadIdx.x;

    if (bid < NGEMM) {
        // ---- proj GEMM: P[r][j] = sum_k Q[r][k]*W[j][k] + b[j]
        int wave = tid >> 6;
        int lane = tid & 63;
        int bm = (bid / 3) * 64;
        int bn = (bid % 3) * 128;
        int wm = (wave & 1) * 32;
        int wn = (wave >> 1) * 64;
        int lr = lane & 15;
        int lk = (lane >> 4) * 8;

        f32x4 acc[2][4] = {};
        for (int k0 = 0; k0 < 256; k0 += 32) {
            bf16x8 afrag[2], bfrag[4];
            #pragma unroll
            for (int i = 0; i < 2; ++i) {
                int row = bm + wm + i * 16 + lr;
                row = row < M ? row : M - 1;     // clamp; stores are guarded
                afrag[i] = cvt8(Q + (size_t)row * 256 + k0 + lk);
            }
            #pragma unroll
            for (int j = 0; j < 4; ++j) {
                int n = bn + wn + j * 16 + lr;
                const float* wp = (n < 256) ? (Woff + (size_t)n * 256)
                                            : (Wattn + (size_t)(n - 256) * 256);
                bfrag[j] = cvt8(wp + k0 + lk);
            }
            #pragma unroll
            for (int i = 0; i < 2; ++i)
                #pragma unroll
                for (int j = 0; j < 4; ++j)
                    acc[i][j] = __builtin_amdgcn_mfma_f32_16x16x32_bf16(
                        afrag[i], bfrag[j], acc[i][j], 0, 0, 0);
        }
        #pragma unroll
        for (int i = 0; i < 2; ++i) {
            int mbase = bm + wm + i * 16 + (lane >> 4) * 4;
            #pragma unroll
            for (int j = 0; j < 4; ++j) {
                int n = bn + wn + j * 16 + (lane & 15);
                float bias = (n < 256) ? boff[n] : battn[n - 256];
                #pragma unroll
                for (int r = 0; r < 4; ++r) {
                    int row = mbase + r;
                    if (row < M) P[(size_t)row * 384 + n] = acc[i][j][r] + bias;
                }
            }
        }
    } else {
        // ---- transpose tile: (n, 32, S) fp32 -> (n, S, 32) bf16
        int tb = bid - NGEMM;
        int bx = tb % 680;
        int n  = tb / 680;
        const float* in; int S; size_t ob; int tile;
        if (bx < 512)      { in = v0; S = 16384; ob = LB0; tile = bx; }
        else if (bx < 640) { in = v1; S = 4096;  ob = LB1; tile = bx - 512; }
        else if (bx < 672) { in = v2; S = 1024;  ob = LB2; tile = bx - 640; }
        else               { in = v3; S = 256;   ob = LB3; tile = bx - 672; }

        int tx = tid & 31;
        int ty = tid >> 5;
        int s0 = tile * 32;
        const float* pin = in + (size_t)n * 32 * S;
        #pragma unroll
        for (int c = ty; c < 32; c += 8) {
            t[c][tx] = pin[(size_t)c * S + s0 + tx];
        }
        __syncthreads();
        unsigned short* pout = vt + ob + (size_t)n * S * 32;
        #pragma unroll
        for (int r = ty; r < 32; r += 8) {
            pout[(size_t)(s0 + r) * 32 + tx] = f2bf(t[tx][r]);
        }
    }
}

// ---------------------------------------------------------------------------
// sampling, head-partitioned (bid&7 = h -> XCD h). block = (h, b, 16 queries).
// phase 1 (all 256 thr, tid=(q,lp)): shuffle softmax + corners, attn folded;
//   s_iw row (q>>1)*388 + (p*8+l*2+(q&1))*12 dwords -> b128 reads <=2-way.
// phase 2: tid = (l, q, c8); per-p: 2 LDS int4 + 4 ushort8 gathers (16B —
//   half the vmem instructions of the 8B version) + 32 FMA; LDS-reduce over l.
// ---------------------------------------------------------------------------
__global__ __launch_bounds__(256) void ms_deform_kernel(
    const float* __restrict__ rp,            // (BS, NQ, L, NK, 2)
    const float* __restrict__ proj,          // (BS*LEN_Q, 384)
    const unsigned short* __restrict__ vt,   // transposed bf16 values
    float* __restrict__ out)                 // (BS, LEN_Q, 256)
{
    int bid = blockIdx.x;
    int h   = bid & 7;            // XCD id under round-robin dispatch
    int b   = (bid >> 3) & 3;
    int qc  = bid >> 5;           // 0..318
    int q0  = qc * 16;

    __shared__ int s_iw[3104];               // 8 groups x 388 dwords
    __shared__ float4 s_red4[2][256];

    int tid = threadIdx.x;

    // phase 1: element (q = tid>>4, lp = tid&15)
    {
        int qL = tid >> 4;
        int lp = tid & 15;
        int l  = lp >> 2;
        int p  = lp & 3;
        int q  = q0 + qL;
        int qq = q < LEN_Q ? q : LEN_Q - 1;
        const float* prow = proj + (size_t)(b * LEN_Q + qq) * 384;

        // shuffle softmax over this head's 16 logits (16-lane groups)
        float g = prow[256 + h * 16 + lp];
        float mx = g;
        mx = fmaxf(mx, __shfl_xor(mx, 1, 16));
        mx = fmaxf(mx, __shfl_xor(mx, 2, 16));
        mx = fmaxf(mx, __shfl_xor(mx, 4, 16));
        mx = fmaxf(mx, __shfl_xor(mx, 8, 16));
        float e = __expf(g - mx);
        float s = e;
        s += __shfl_xor(s, 1, 16);
        s += __shfl_xor(s, 2, 16);
        s += __shfl_xor(s, 4, 16);
        s += __shfl_xor(s, 8, 16);
        float a = (q < LEN_Q) ? (e / s) : 0.f;

        int Wl = 128 >> l;            // square levels: 128,64,32,16
        float ww = (float)Wl;
        int qi = qq / NK;
        int ki = qq - qi * NK;
        size_t rbase = ((((size_t)b * NQ + qi) * N_LEVELS + l) * NK + ki) * 2;
        float rx = rp[rbase + 0];
        float ry = rp[rbase + 1];
        int oj = (h * 16 + lp) * 2;
        float ox = prow[oj], oy = prow[oj + 1];
        // grid_sample align_corners=False: x = loc*w - 0.5
        float x = (rx + ox / ww) * ww - 0.5f;
        float y = (ry + oy / ww) * ww - 0.5f;
        float x0f = floorf(x), y0f = floorf(y);
        float wx1 = x - x0f, wy1 = y - y0f;
        float wx0 = 1.f - wx1, wy0 = 1.f - wy1;
        int x0 = (int)x0f, y0 = (int)y0f;

        int* wrow = s_iw + (qL >> 1) * 388 + (p * 8 + l * 2 + (qL & 1)) * 12;
        #pragma unroll
        for (int corner = 0; corner < 4; ++corner) {
            int xi = x0 + (corner & 1);
            int yi = y0 + (corner >> 1);
            float wgt = ((corner & 1) ? wx1 : wx0) * ((corner >> 1) ? wy1 : wy0);
            bool valid = (xi >= 0) && (xi < Wl) && (yi >= 0) && (yi < Wl);
            int2 iw;
            iw.x = valid ? (yi * Wl + xi) * HD : 0;   // ushort-unit index
            iw.y = __float_as_int(valid ? wgt * a : 0.f);
            *(int2*)(wrow + corner * 2) = iw;
        }
    }
    __syncthreads();

    // phase 2: tid = l*64 + qL*4 + c8
    int l  = tid >> 6;
    int qL = (tid >> 2) & 15;
    int c8 = tid & 3;
    int n  = b * N_HEADS + h;
    const size_t lb[4]  = {LB0, LB1, LB2, LB3};
    const int    Ssz[4] = {16384, 4096, 1024, 256};

    const unsigned short* vbase = vt + lb[l] + (size_t)n * Ssz[l] * HD + c8 * 8;
    const int* rrow0 = s_iw + (qL >> 1) * 388 + (l * 2 + (qL & 1)) * 12;

    float4 accA = make_float4(0.f, 0.f, 0.f, 0.f);
    float4 accB = make_float4(0.f, 0.f, 0.f, 0.f);
    #pragma unroll
    for (int p = 0; p < 4; ++p) {
        const int* rr = rrow0 + p * 96;                 // p*8 rows * 12 dwords
        int4 A  = *(const int4*)rr;                     // corners 0,1
        int4 Bv = *(const int4*)(rr + 4);               // corners 2,3
        ushort8_t u0 = *(const ushort8_t*)(vbase + A.x);
        ushort8_t u1 = *(const ushort8_t*)(vbase + A.z);
        ushort8_t u2 = *(const ushort8_t*)(vbase + Bv.x);
        ushort8_t u3 = *(const ushort8_t*)(vbase + Bv.z);
        float w0 = __int_as_float(A.y);
        float w1 = __int_as_float(A.w);
        float w2 = __int_as_float(Bv.y);
        float w3 = __int_as_float(Bv.w);
        accA.x += w0 * bf2f(u0[0]) + w1 * bf2f(u1[0]) + w2 * bf2f(u2[0]) + w3 * bf2f(u3[0]);
        accA.y += w0 * bf2f(u0[1]) + w1 * bf2f(u1[1]) + w2 * bf2f(u2[1]) + w3 * bf2f(u3[1]);
        accA.z += w0 * bf2f(u0[2]) + w1 * bf2f(u1[2]) + w2 * bf2f(u2[2]) + w3 * bf2f(u3[2]);
        accA.w += w0 * bf2f(u0[3]) + w1 * bf2f(u1[3]) + w2 * bf2f(u2[3]) + w3 * bf2f(u3[3]);
        accB.x += w0 * bf2f(u0[4]) + w1 * bf2f(u1[4]) + w2 * bf2f(u2[4]) + w3 * bf2f(u3[4]);
        accB.y += w0 * bf2f(u0[5]) + w1 * bf2f(u1[5]) + w2 * bf2f(u2[5]) + w3 * bf2f(u3[5]);
        accB.z += w0 * bf2f(u0[6]) + w1 * bf2f(u1[6]) + w2 * bf2f(u2[6]) + w3 * bf2f(u3[6]);
        accB.w += w0 * bf2f(u0[7]) + w1 * bf2f(u1[7]) + w2 * bf2f(u2[7]) + w3 * bf2f(u3[7]);
    }

    s_red4[0][tid] = accA;
    s_red4[1][tid] = accB;
    __syncthreads();
    if (tid < 128) {
        int qo = tid >> 3;            // 0..15
        int co = (tid >> 1) & 3;      // c8
        int hf = tid & 1;             // which half (4 channels)
        int base = qo * 4 + co;
        float4 a0 = s_red4[hf][base];
        float4 a1 = s_red4[hf][base + 64];
        float4 a2 = s_red4[hf][base + 128];
        float4 a3 = s_red4[hf][base + 192];
        float4 o;
        o.x = a0.x + a1.x + a2.x + a3.x;
        o.y = a0.y + a1.y + a2.y + a3.y;
        o.z = a0.z + a1.z + a2.z + a3.z;
        o.w = a0.w + a1.w + a2.w + a3.w;
        int q = q0 + qo;
        if (q < LEN_Q)
            *(float4*)(out + (size_t)(b * LEN_Q + q) * 256 + h * 32 + co * 8 + hf * 4) = o;
    }
}

// ---------------------------------------------------------------------------
extern "C" void kernel_launch(void* const* d_in, const int* in_sizes, int n_in,
                              void* d_out, int out_size, void* d_ws, size_t ws_size,
                              hipStream_t stream)
{
    const float* query = (const float*)d_in[0];
    const float* refp  = (const float*)d_in[1];
    const float* v0    = (const float*)d_in[2];
    const float* v1    = (const float*)d_in[3];
    const float* v2    = (const float*)d_in[4];
    const float* v3    = (const float*)d_in[5];
    const float* Woff  = (const float*)d_in[6];
    const float* boff  = (const float*)d_in[7];
    const float* Wattn = (const float*)d_in[8];
    const float* battn = (const float*)d_in[9];
    float* out = (float*)d_out;
    unsigned short* vt = (unsigned short*)d_ws;
    float* proj = (float*)(vt + VT_TOTAL);    // 44.6 MB offset, 4B-aligned

    int M = BS * LEN_Q;                       // 20400

    // 1) fused prep: GEMM blocks + transpose blocks in one launch (overlap)
    prep_kernel<<<NGEMM + NTRANS, 256, 0, stream>>>(
        query, Woff, boff, Wattn, battn, v0, v1, v2, v3, vt, proj, M);

    // 2) sampling: (319 q-chunks) x (4 b) x (8 h); blockIdx%8 = h -> XCD h
    ms_deform_kernel<<<319 * 32, 256, 0, stream>>>(refp, proj, vt, out);
}

// Round 13
// 128.090 us; speedup vs baseline: 1.1103x; 1.1103x over previous
//
#include <hip/hip_runtime.h>
#include <math.h>

#define BS        4
#define NQ        300
#define NK        17
#define LEN_Q     5100          // NQ*NK
#define N_HEADS   8
#define N_LEVELS  4
#define N_POINTS  4
#define D_MODEL   256
#define HD        32            // D_MODEL / N_HEADS

// transposed-value level bases (ushort/bf16 units), layout vt[l][n][s][c]
#define LB0 0
#define LB1 16777216            // + 32*16384*32
#define LB2 20971520            // + 32*4096*32
#define LB3 22020096            // + 32*1024*32
#define VT_TOTAL 22282240       // ushorts (44.6 MB)

typedef __attribute__((ext_vector_type(8))) short bf16x8;
typedef __attribute__((ext_vector_type(8))) unsigned short ushort8_t;
typedef __attribute__((ext_vector_type(4))) float f32x4;

// ---------------------------------------------------------------------------
// bf16 helpers (RNE)
// ---------------------------------------------------------------------------
__device__ __forceinline__ unsigned short f2bf(float x) {
    unsigned u = __float_as_uint(x);
    unsigned r = (u + 0x7fffu + ((u >> 16) & 1u)) >> 16;
    return (unsigned short)r;
}
__device__ __forceinline__ float bf2f(unsigned short s) {
    return __uint_as_float((unsigned)s << 16);
}
__device__ __forceinline__ bf16x8 cvt8(const float* __restrict__ p) {
    float4 a = *(const float4*)p;
    float4 b = *(const float4*)(p + 4);
    bf16x8 r;
    r[0] = f2bf(a.x); r[1] = f2bf(a.y); r[2] = f2bf(a.z); r[3] = f2bf(a.w);
    r[4] = f2bf(b.x); r[5] = f2bf(b.y); r[6] = f2bf(b.z); r[7] = f2bf(b.w);
    return r;
}

// ---------------------------------------------------------------------------
// value transpose: (n, 32, S) fp32 -> (n, S, 32) bf16. Own kernel (round-12
// lesson: do NOT fuse heterogeneous block types into one grid).
// block 256, grid (680, 32). float4 reads, ushort2 writes.
// ---------------------------------------------------------------------------
__global__ __launch_bounds__(256) void transpose_bf16_kernel(
    const float* __restrict__ v0, const float* __restrict__ v1,
    const float* __restrict__ v2, const float* __restrict__ v3,
    unsigned short* __restrict__ vt)
{
    __shared__ float t[32][36];       // stride 36: rows 16B-aligned
    int bx = blockIdx.x;
    int n  = blockIdx.y;

    const float* in; int S; size_t ob; int tile;
    if (bx < 512)      { in = v0; S = 16384; ob = LB0; tile = bx; }
    else if (bx < 640) { in = v1; S = 4096;  ob = LB1; tile = bx - 512; }
    else if (bx < 672) { in = v2; S = 1024;  ob = LB2; tile = bx - 640; }
    else               { in = v3; S = 256;   ob = LB3; tile = bx - 672; }

    int tid = threadIdx.x;
    int s0 = tile * 32;

    // read: thread (c = tid>>3, c4 = (tid&7)*4) loads float4 of row c
    int c  = tid >> 3;
    int c4 = (tid & 7) * 4;
    const float* pin = in + (size_t)n * 32 * S;
    *(float4*)&t[c][c4] = *(const float4*)(pin + (size_t)c * S + s0 + c4);
    __syncthreads();

    // write: thread (r = tid>>4 (+16), c2 = (tid&15)*2) stores ushort2
    unsigned short* pout = vt + ob + (size_t)n * S * 32;
    int r0 = tid >> 4;
    int c2 = (tid & 15) * 2;
    #pragma unroll
    for (int rr = 0; rr < 2; ++rr) {
        int r = r0 + rr * 16;
        ushort2 w;
        w.x = f2bf(t[c2][r]);
        w.y = f2bf(t[c2 + 1][r]);
        *(ushort2*)(pout + (size_t)(s0 + r) * 32 + c2) = w;
    }
}

// ---------------------------------------------------------------------------
// MFMA proj GEMM: P[r][j] = sum_k Q[r][k]*W[j][k] + b[j]
// W = [W_off (256 rows) ; W_attn (128 rows)], K = 256, N = 384, M = 20400
// block = 256 thr (4 waves), tile BM=64 x BN=128; wave = 32x64 (2x4 frags).
// ---------------------------------------------------------------------------
__global__ __launch_bounds__(256) void proj_gemm_mfma(
    const float* __restrict__ Q,
    const float* __restrict__ Woff, const float* __restrict__ boff,
    const float* __restrict__ Wattn, const float* __restrict__ battn,
    float* __restrict__ P, int M)
{
    int tid  = threadIdx.x;
    int wave = tid >> 6;
    int lane = tid & 63;
    int bm = blockIdx.y * 64;           // grid.y: 319 row-blocks
    int bn = blockIdx.x * 128;          // grid.x: 3 col-blocks (n fastest)
    int wm = (wave & 1) * 32;
    int wn = (wave >> 1) * 64;
    int lr = lane & 15;
    int lk = (lane >> 4) * 8;

    f32x4 acc[2][4] = {};
    for (int k0 = 0; k0 < 256; k0 += 32) {
        bf16x8 afrag[2], bfrag[4];
        #pragma unroll
        for (int i = 0; i < 2; ++i) {
            int row = bm + wm + i * 16 + lr;
            row = row < M ? row : M - 1;         // clamp; stores are guarded
            afrag[i] = cvt8(Q + (size_t)row * 256 + k0 + lk);
        }
        #pragma unroll
        for (int j = 0; j < 4; ++j) {
            int n = bn + wn + j * 16 + lr;
            const float* wp = (n < 256) ? (Woff + (size_t)n * 256)
                                        : (Wattn + (size_t)(n - 256) * 256);
            bfrag[j] = cvt8(wp + k0 + lk);
        }
        #pragma unroll
        for (int i = 0; i < 2; ++i)
            #pragma unroll
            for (int j = 0; j < 4; ++j)
                acc[i][j] = __builtin_amdgcn_mfma_f32_16x16x32_bf16(
                    afrag[i], bfrag[j], acc[i][j], 0, 0, 0);
    }

    #pragma unroll
    for (int i = 0; i < 2; ++i) {
        int mbase = bm + wm + i * 16 + (lane >> 4) * 4;
        #pragma unroll
        for (int j = 0; j < 4; ++j) {
            int n = bn + wn + j * 16 + (lane & 15);
            float bias = (n < 256) ? boff[n] : battn[n - 256];
            #pragma unroll
            for (int r = 0; r < 4; ++r) {
                int row = mbase + r;
                if (row < M) P[(size_t)row * 384 + n] = acc[i][j][r] + bias;
            }
        }
    }
}

// ---------------------------------------------------------------------------
// sampling, head-partitioned (bid&7 = h -> XCD h). block = (h, b, 16 queries).
// phase 1 (all 256 thr, tid=(q,lp)): shuffle softmax + corners, attn folded;
//   s_iw row (q>>1)*388 + (p*8+l*2+(q&1))*12 dwords -> b128 reads <=2-way.
// phase 2: tid = (l, q, c8); per-p: 2 LDS int4 + 4 ushort8 gathers (16B) +
//   32 FMA; LDS-reduce over l. (round 12: 59.7 -> ~12 us, keep untouched)
// ---------------------------------------------------------------------------
__global__ __launch_bounds__(256) void ms_deform_kernel(
    const float* __restrict__ rp,            // (BS, NQ, L, NK, 2)
    const float* __restrict__ proj,          // (BS*LEN_Q, 384)
    const unsigned short* __restrict__ vt,   // transposed bf16 values
    float* __restrict__ out)                 // (BS, LEN_Q, 256)
{
    int bid = blockIdx.x;
    int h   = bid & 7;            // XCD id under round-robin dispatch
    int b   = (bid >> 3) & 3;
    int qc  = bid >> 5;           // 0..318
    int q0  = qc * 16;

    __shared__ int s_iw[3104];               // 8 groups x 388 dwords
    __shared__ float4 s_red4[2][256];

    int tid = threadIdx.x;

    // phase 1: element (q = tid>>4, lp = tid&15)
    {
        int qL = tid >> 4;
        int lp = tid & 15;
        int l  = lp >> 2;
        int p  = lp & 3;
        int q  = q0 + qL;
        int qq = q < LEN_Q ? q : LEN_Q - 1;
        const float* prow = proj + (size_t)(b * LEN_Q + qq) * 384;

        // shuffle softmax over this head's 16 logits (16-lane groups)
        float g = prow[256 + h * 16 + lp];
        float mx = g;
        mx = fmaxf(mx, __shfl_xor(mx, 1, 16));
        mx = fmaxf(mx, __shfl_xor(mx, 2, 16));
        mx = fmaxf(mx, __shfl_xor(mx, 4, 16));
        mx = fmaxf(mx, __shfl_xor(mx, 8, 16));
        float e = __expf(g - mx);
        float s = e;
        s += __shfl_xor(s, 1, 16);
        s += __shfl_xor(s, 2, 16);
        s += __shfl_xor(s, 4, 16);
        s += __shfl_xor(s, 8, 16);
        float a = (q < LEN_Q) ? (e / s) : 0.f;

        int Wl = 128 >> l;            // square levels: 128,64,32,16
        float ww = (float)Wl;
        int qi = qq / NK;
        int ki = qq - qi * NK;
        size_t rbase = ((((size_t)b * NQ + qi) * N_LEVELS + l) * NK + ki) * 2;
        float rx = rp[rbase + 0];
        float ry = rp[rbase + 1];
        int oj = (h * 16 + lp) * 2;
        float ox = prow[oj], oy = prow[oj + 1];
        // grid_sample align_corners=False: x = loc*w - 0.5
        float x = (rx + ox / ww) * ww - 0.5f;
        float y = (ry + oy / ww) * ww - 0.5f;
        float x0f = floorf(x), y0f = floorf(y);
        float wx1 = x - x0f, wy1 = y - y0f;
        float wx0 = 1.f - wx1, wy0 = 1.f - wy1;
        int x0 = (int)x0f, y0 = (int)y0f;

        int* wrow = s_iw + (qL >> 1) * 388 + (p * 8 + l * 2 + (qL & 1)) * 12;
        #pragma unroll
        for (int corner = 0; corner < 4; ++corner) {
            int xi = x0 + (corner & 1);
            int yi = y0 + (corner >> 1);
            float wgt = ((corner & 1) ? wx1 : wx0) * ((corner >> 1) ? wy1 : wy0);
            bool valid = (xi >= 0) && (xi < Wl) && (yi >= 0) && (yi < Wl);
            int2 iw;
            iw.x = valid ? (yi * Wl + xi) * HD : 0;   // ushort-unit index
            iw.y = __float_as_int(valid ? wgt * a : 0.f);
            *(int2*)(wrow + corner * 2) = iw;
        }
    }
    __syncthreads();

    // phase 2: tid = l*64 + qL*4 + c8
    int l  = tid >> 6;
    int qL = (tid >> 2) & 15;
    int c8 = tid & 3;
    int n  = b * N_HEADS + h;
    const size_t lb[4]  = {LB0, LB1, LB2, LB3};
    const int    Ssz[4] = {16384, 4096, 1024, 256};

    const unsigned short* vbase = vt + lb[l] + (size_t)n * Ssz[l] * HD + c8 * 8;
    const int* rrow0 = s_iw + (qL >> 1) * 388 + (l * 2 + (qL & 1)) * 12;

    float4 accA = make_float4(0.f, 0.f, 0.f, 0.f);
    float4 accB = make_float4(0.f, 0.f, 0.f, 0.f);
    #pragma unroll
    for (int p = 0; p < 4; ++p) {
        const int* rr = rrow0 + p * 96;                 // p*8 rows * 12 dwords
        int4 A  = *(const int4*)rr;                     // corners 0,1
        int4 Bv = *(const int4*)(rr + 4);               // corners 2,3
        ushort8_t u0 = *(const ushort8_t*)(vbase + A.x);
        ushort8_t u1 = *(const ushort8_t*)(vbase + A.z);
        ushort8_t u2 = *(const ushort8_t*)(vbase + Bv.x);
        ushort8_t u3 = *(const ushort8_t*)(vbase + Bv.z);
        float w0 = __int_as_float(A.y);
        float w1 = __int_as_float(A.w);
        float w2 = __int_as_float(Bv.y);
        float w3 = __int_as_float(Bv.w);
        accA.x += w0 * bf2f(u0[0]) + w1 * bf2f(u1[0]) + w2 * bf2f(u2[0]) + w3 * bf2f(u3[0]);
        accA.y += w0 * bf2f(u0[1]) + w1 * bf2f(u1[1]) + w2 * bf2f(u2[1]) + w3 * bf2f(u3[1]);
        accA.z += w0 * bf2f(u0[2]) + w1 * bf2f(u1[2]) + w2 * bf2f(u2[2]) + w3 * bf2f(u3[2]);
        accA.w += w0 * bf2f(u0[3]) + w1 * bf2f(u1[3]) + w2 * bf2f(u2[3]) + w3 * bf2f(u3[3]);
        accB.x += w0 * bf2f(u0[4]) + w1 * bf2f(u1[4]) + w2 * bf2f(u2[4]) + w3 * bf2f(u3[4]);
        accB.y += w0 * bf2f(u0[5]) + w1 * bf2f(u1[5]) + w2 * bf2f(u2[5]) + w3 * bf2f(u3[5]);
        accB.z += w0 * bf2f(u0[6]) + w1 * bf2f(u1[6]) + w2 * bf2f(u2[6]) + w3 * bf2f(u3[6]);
        accB.w += w0 * bf2f(u0[7]) + w1 * bf2f(u1[7]) + w2 * bf2f(u2[7]) + w3 * bf2f(u3[7]);
    }

    s_red4[0][tid] = accA;
    s_red4[1][tid] = accB;
    __syncthreads();
    if (tid < 128) {
        int qo = tid >> 3;            // 0..15
        int co = (tid >> 1) & 3;      // c8
        int hf = tid & 1;             // which half (4 channels)
        int base = qo * 4 + co;
        float4 a0 = s_red4[hf][base];
        float4 a1 = s_red4[hf][base + 64];
        float4 a2 = s_red4[hf][base + 128];
        float4 a3 = s_red4[hf][base + 192];
        float4 o;
        o.x = a0.x + a1.x + a2.x + a3.x;
        o.y = a0.y + a1.y + a2.y + a3.y;
        o.z = a0.z + a1.z + a2.z + a3.z;
        o.w = a0.w + a1.w + a2.w + a3.w;
        int q = q0 + qo;
        if (q < LEN_Q)
            *(float4*)(out + (size_t)(b * LEN_Q + q) * 256 + h * 32 + co * 8 + hf * 4) = o;
    }
}

// ---------------------------------------------------------------------------
extern "C" void kernel_launch(void* const* d_in, const int* in_sizes, int n_in,
                              void* d_out, int out_size, void* d_ws, size_t ws_size,
                              hipStream_t stream)
{
    const float* query = (const float*)d_in[0];
    const float* refp  = (const float*)d_in[1];
    const float* v0    = (const float*)d_in[2];
    const float* v1    = (const float*)d_in[3];
    const float* v2    = (const float*)d_in[4];
    const float* v3    = (const float*)d_in[5];
    const float* Woff  = (const float*)d_in[6];
    const float* boff  = (const float*)d_in[7];
    const float* Wattn = (const float*)d_in[8];
    const float* battn = (const float*)d_in[9];
    float* out = (float*)d_out;
    unsigned short* vt = (unsigned short*)d_ws;
    float* proj = (float*)(vt + VT_TOTAL);    // 44.6 MB offset, 4B-aligned

    int M = BS * LEN_Q;                       // 20400

    // 1) value transpose -> bf16 (n, s, c)
    transpose_bf16_kernel<<<dim3(680, 32), 256, 0, stream>>>(
        v0, v1, v2, v3, vt);

    // 2) proj MFMA GEMM -> (M, 384) = [off(256) | attn_logits(128)]
    proj_gemm_mfma<<<dim3(3, (M + 63) / 64), 256, 0, stream>>>(
        query, Woff, boff, Wattn, battn, proj, M);

    // 3) sampling: (319 q-chunks) x (4 b) x (8 h); blockIdx%8 = h -> XCD h
    ms_deform_kernel<<<319 * 32, 256, 0, stream>>>(refp, proj, vt, out);
}